// Round 7
// baseline (131.013 us; speedup 1.0000x reference)
//
#include <hip/hip_runtime.h>

#define NN   21   // nodes
#define NE   60   // edges (before self-loops)
#define FD   3    // input features
#define HD   32   // hidden
#define PP   64   // periods
#define OUTC 6    // output channels
#define LOG2E 1.44269504088896f

#if defined(__has_builtin)
#  if __has_builtin(__builtin_amdgcn_exp2f)
#    define EXP2(x) __builtin_amdgcn_exp2f(x)
#  else
#    define EXP2(x) exp2f(x)
#  endif
#else
#  define EXP2(x) exp2f(x)
#endif
#define RCP(x) __builtin_amdgcn_rcpf(x)

// ---------------------------------------------------------------------------
// Fully fused: ONE kernel, one block (512 thr = 8 waves) per batch element.
// Per-block parallel setup (~1us): deg scatter -> A[d][s] (rsqrt inline),
// W' = W@lW_top (log2e-prescaled), probs = softmax(att), Sc, M.
// Algebra (H=0): Hn = (1-Z)*tanh(..); no nonlinearity between l1 and l2:
//   out[c,p] = sum_o G[c,o]*l1W[o,p] + M[c,p],   M = Sc[c]*l1b[p]+l2b[c]
//   G[c,o]   = sum_n l2W[n,c]*relu(sum_p probs[p]*(1-Z)*tanh)
// Gate eval (3 trans, 11 VALU): pr*(1-Z)*tanh = fmaf(pr,e2,-pr)*rcp((1+ea)(1+e2))
// T14 latency splits: x and l1W global loads issued early, LDS-written late.
// ---------------------------------------------------------------------------
#define EVAL(Y0,Y1,Y2,PR) do {                                                  \
    float az0_ = fmaf((Y2), wz02, fmaf((Y1), wz01, fmaf((Y0), wz00, bz0)));     \
    float ah0_ = fmaf((Y2), wh02, fmaf((Y1), wh01, fmaf((Y0), wh00, bh0)));     \
    float ea0_ = EXP2(az0_), e20_ = EXP2(ah0_);                                 \
    float r0_  = RCP((1.f + ea0_) * (1.f + e20_));                              \
    acc0 = fmaf(fmaf((PR), e20_, -(PR)), r0_, acc0);                            \
    float az1_ = fmaf((Y2), wz12, fmaf((Y1), wz11, fmaf((Y0), wz10, bz1)));     \
    float ah1_ = fmaf((Y2), wh12, fmaf((Y1), wh11, fmaf((Y0), wh10, bh1)));     \
    float ea1_ = EXP2(az1_), e21_ = EXP2(ah1_);                                 \
    float r1_  = RCP((1.f + ea1_) * (1.f + e21_));                              \
    acc1 = fmaf(fmaf((PR), e21_, -(PR)), r1_, acc1);                            \
} while (0)

__global__ __launch_bounds__(512, 8) void fused_k(
    const float* __restrict__ x,   const int* __restrict__ edge,
    const float* __restrict__ Wz,  const float* __restrict__ bz,
    const float* __restrict__ Wh,  const float* __restrict__ bh,
    const float* __restrict__ lzW, const float* __restrict__ lzb,
    const float* __restrict__ lhW, const float* __restrict__ lhb,
    const float* __restrict__ att,
    const float* __restrict__ l1W, const float* __restrict__ l1b,
    const float* __restrict__ l2W, const float* __restrict__ l2b,
    float* __restrict__ out)
{
    // LDS floats: 4032+4032+504+352+672+192+384 = 10168 -> 40672 B
    // 4 blocks x 40672 = 162688 < 163840 -> 4 blocks/CU, 32 waves/CU (max)
    __shared__ __align__(16) float Xs[NN * FD * PP]; // x[b]; post-stage1: l1W overlay
    __shared__ __align__(16) float Ys[NN * FD * PP]; // Y = A@X
    __shared__ __align__(16) float AsP[NN * 24];     // padded adjacency
    __shared__ __align__(16) float Cs[352];          // W'z|W'h|b'z|b'h|probs|deg|Sc
    __shared__ float Hs[NN * HD];
    __shared__ float G[OUTC * HD];
    __shared__ __align__(16) float Ms[OUTC * PP];    // M[c][p]

    const int t = threadIdx.x;
    const int b = blockIdx.x;
    const float* xb = x + (size_t)b * (NN * FD * PP);

    // ---- Phase A: issue x loads FIRST (T14), zero A / init deg under the
    //      latency, then LDS-write.
    {
        const float4* xb4 = (const float4*)xb;
        float4 xr0 = xb4[t];
        float4 xr1 = {0.f,0.f,0.f,0.f};
        if (t < 496) xr1 = xb4[512 + t];              // 1008 float4 total

        for (int i = t; i < NN * 24; i += 512) AsP[i] = 0.f;
        if (t < NN) Cs[320 + t] = 1.f;                // deg = 1 (self-loop)

        float4* Xs4 = (float4*)Xs;
        Xs4[t] = xr0;
        if (t < 496) Xs4[512 + t] = xr1;
    }
    __syncthreads();

    // ---- Phase B: deg scatter | W' fusion | biases | softmax | Sc (disjoint)
    if (t < NE) {
        atomicAdd(&Cs[320 + edge[NE + t]], 1.f);
    } else if (t >= 64 && t < 160) {                  // W' = W @ lW_top, scaled
        int i = t - 64, f = i >> 5, o = i & 31;
        float az = 0.f, ah = 0.f;
        #pragma unroll
        for (int k = 0; k < HD; ++k) {
            az = fmaf(Wz[f * HD + k], lzW[k * HD + o], az);
            ah = fmaf(Wh[f * HD + k], lhW[k * HD + o], ah);
        }
        Cs[i] = az * LOG2E;                           // W'z
        Cs[96 + i] = ah * (2.f * LOG2E);              // W'h
    } else if (t >= 160 && t < 192) {                 // fused biases
        int o = t - 160;
        float az = lzb[o], ah = lhb[o];
        #pragma unroll
        for (int k = 0; k < HD; ++k) {
            az = fmaf(bz[k], lzW[k * HD + o], az);
            ah = fmaf(bh[k], lhW[k * HD + o], ah);
        }
        Cs[192 + o] = az * LOG2E;
        Cs[224 + o] = ah * (2.f * LOG2E);
    } else if (t >= 192 && t < 256) {                 // softmax(att), wave 3
        int l = t - 192;
        float a = att[l], m = a;
        #pragma unroll
        for (int msk = 32; msk >= 1; msk >>= 1) m = fmaxf(m, __shfl_xor(m, msk, 64));
        float e = EXP2((a - m) * LOG2E);
        float ssum = e;
        #pragma unroll
        for (int msk = 32; msk >= 1; msk >>= 1) ssum += __shfl_xor(ssum, msk, 64);
        Cs[256 + l] = e / ssum;
    } else if (t >= 256 && t < 256 + OUTC) {          // Sc[c] = sum_n l2W[n][c]
        int c = t - 256;
        float s = 0.f;
        for (int n = 0; n < NN; ++n) s += l2W[n * OUTC + c];
        Cs[344 + c] = s;
    }
    __syncthreads();

    // ---- Phase C: adjacency atomics (lanes <85) || M[c,p] (lanes >=128)
    if (t < NE) {
        int s = edge[t], d = edge[NE + t];
        atomicAdd(&AsP[d * 24 + s], rsqrtf(Cs[320 + s]) * rsqrtf(Cs[320 + d]));
    } else if (t >= 64 && t < 64 + NN) {
        int n = t - 64;
        atomicAdd(&AsP[n * 24 + n], RCP(Cs[320 + n]));  // dinv^2 = 1/deg
    }
    if (t >= 128) {                                   // 384 lanes == OUTC*PP
        int i = t - 128;
        int c = i >> 6, p = i & 63;
        Ms[i] = fmaf(Cs[344 + c], l1b[p], l2b[c]);
    }
    __syncthreads();

    // ---- issue l1W load early (T14): consumed after stage-1 barrier
    float4 l1w_reg = ((const float4*)l1W)[t];         // 512 x 16B = 2048 floats

    // ---- Stage 1: Y = A @ X, skipping zero A entries (A ~82% zeros)
    {
        const float4* Xs4 = (const float4*)Xs;
        float4* Ys4 = (float4*)Ys;
        for (int i = t; i < NN * FD * PP / 4; i += 512) {
            const int p4 = i & 15;
            const int fn = i >> 4;            // n*3 + f
            const int n  = fn / 3;
            const int f  = fn - n * 3;
            const float4* An4 = (const float4*)(AsP + n * 24);
            float4 acc = {0.f, 0.f, 0.f, 0.f};
            #pragma unroll
            for (int mq = 0; mq < 6; ++mq) {
                const float4 a = An4[mq];
                if (a.x != 0.f) { const float4 xv = Xs4[((mq*4+0)*3+f)*16 + p4];
                    acc.x=fmaf(a.x,xv.x,acc.x); acc.y=fmaf(a.x,xv.y,acc.y);
                    acc.z=fmaf(a.x,xv.z,acc.z); acc.w=fmaf(a.x,xv.w,acc.w); }
                if (a.y != 0.f) { const float4 xv = Xs4[((mq*4+1)*3+f)*16 + p4];
                    acc.x=fmaf(a.y,xv.x,acc.x); acc.y=fmaf(a.y,xv.y,acc.y);
                    acc.z=fmaf(a.y,xv.z,acc.z); acc.w=fmaf(a.y,xv.w,acc.w); }
                if (a.z != 0.f) { const float4 xv = Xs4[((mq*4+2)*3+f)*16 + p4];
                    acc.x=fmaf(a.z,xv.x,acc.x); acc.y=fmaf(a.z,xv.y,acc.y);
                    acc.z=fmaf(a.z,xv.z,acc.z); acc.w=fmaf(a.z,xv.w,acc.w); }
                if (a.w != 0.f) { const float4 xv = Xs4[((mq*4+3)*3+f)*16 + p4];
                    acc.x=fmaf(a.w,xv.x,acc.x); acc.y=fmaf(a.w,xv.y,acc.y);
                    acc.z=fmaf(a.w,xv.z,acc.z); acc.w=fmaf(a.w,xv.w,acc.w); }
            }
            Ys4[fn * 16 + p4] = acc;
        }
    }
    __syncthreads();

    // ---- l1W -> dead Xs region (load already in flight since before stage 1)
    ((float4*)Xs)[t] = l1w_reg;

    // ---- Stage 2: Hpool[n][o] = sum_p probs[p]*(1-Z)*tanh ; relu fused
    // lane: ps = t&7 (8 p's), o-pair = (t>>3)&15, n-offset = t>>7; p-sum via shfl
    {
        const int ps = t & 7;
        const int og = (t >> 3) & 15;
        const int c4 = t >> 7;                        // 0..3, wave-uniform
        const int o0 = og * 2, o1 = o0 + 1;
        const float wz00 = Cs[o0],     wz01 = Cs[32+o0],  wz02 = Cs[64+o0];
        const float wz10 = Cs[o1],     wz11 = Cs[32+o1],  wz12 = Cs[64+o1];
        const float wh00 = Cs[96+o0],  wh01 = Cs[128+o0], wh02 = Cs[160+o0];
        const float wh10 = Cs[96+o1],  wh11 = Cs[128+o1], wh12 = Cs[160+o1];
        const float bz0  = Cs[192+o0], bz1  = Cs[192+o1];
        const float bh0  = Cs[224+o0], bh1  = Cs[224+o1];
        const float4 pr0 = *(const float4*)&Cs[256 + ps*8];
        const float4 pr1 = *(const float4*)&Cs[256 + ps*8 + 4];
        #pragma unroll
        for (int s = 0; s < 6; ++s) {
            const int n = c4 + 4 * s;
            if (n < NN) {                             // wave-uniform guard
                const float4* Yn4 = (const float4*)(Ys + n * FD * PP) + ps * 2;
                float acc0 = 0.f, acc1 = 0.f;
                float4 y0 = Yn4[0], y1 = Yn4[16], y2 = Yn4[32];
                EVAL(y0.x,y1.x,y2.x, pr0.x); EVAL(y0.y,y1.y,y2.y, pr0.y);
                EVAL(y0.z,y1.z,y2.z, pr0.z); EVAL(y0.w,y1.w,y2.w, pr0.w);
                y0 = Yn4[1]; y1 = Yn4[17]; y2 = Yn4[33];
                EVAL(y0.x,y1.x,y2.x, pr1.x); EVAL(y0.y,y1.y,y2.y, pr1.y);
                EVAL(y0.z,y1.z,y2.z, pr1.z); EVAL(y0.w,y1.w,y2.w, pr1.w);
                acc0 += __shfl_xor(acc0, 1); acc0 += __shfl_xor(acc0, 2); acc0 += __shfl_xor(acc0, 4);
                acc1 += __shfl_xor(acc1, 1); acc1 += __shfl_xor(acc1, 2); acc1 += __shfl_xor(acc1, 4);
                if (ps == 0) {
                    Hs[n * HD + o0] = fmaxf(acc0, 0.f);
                    Hs[n * HD + o1] = fmaxf(acc1, 0.f);
                }
            }
        }
    }
    __syncthreads();

    // ---- Stage 3': G[c,o] = sum_n l2W[n][c] * Hs[n][o]
    if (t < OUTC * HD) {
        const int c = t >> 5, o = t & 31;
        float g = 0.f;
        #pragma unroll
        for (int n = 0; n < NN; ++n)
            g = fmaf(l2W[n * OUTC + c], Hs[n * HD + o], g);
        G[t] = g;
    }
    __syncthreads();

    // ---- Stage 4': out[b,c,p] = sum_o G[c,o]*l1W[o,p] + M[c,p]
    if (t < OUTC * PP) {
        const int c = t >> 6, p = t & 63;
        const float* Gc = G + c * HD;
        const float* l1Ws = Xs;                       // overlaid [32][64]
        float a0 = 0.f, a1 = 0.f, a2 = 0.f, a3 = 0.f;
        #pragma unroll
        for (int o = 0; o < HD; o += 4) {
            a0 = fmaf(Gc[o+0], l1Ws[(o+0) * PP + p], a0);
            a1 = fmaf(Gc[o+1], l1Ws[(o+1) * PP + p], a1);
            a2 = fmaf(Gc[o+2], l1Ws[(o+2) * PP + p], a2);
            a3 = fmaf(Gc[o+3], l1Ws[(o+3) * PP + p], a3);
        }
        out[(size_t)b * (OUTC * PP) + t] = Ms[t] + (a0 + a1) + (a2 + a3);
    }
}

extern "C" void kernel_launch(void* const* d_in, const int* in_sizes, int n_in,
                              void* d_out, int out_size, void* d_ws, size_t ws_size,
                              hipStream_t stream) {
    const float* x   = (const float*)d_in[0];
    const int*   ei  = (const int*)  d_in[1];
    const float* Wz  = (const float*)d_in[2];
    const float* bz  = (const float*)d_in[3];
    // d_in[4], d_in[5] (W_r, b_r) dead: H=0 -> reset gate never used
    const float* Wh  = (const float*)d_in[6];
    const float* bh  = (const float*)d_in[7];
    const float* lzW = (const float*)d_in[8];
    const float* lzb = (const float*)d_in[9];
    // d_in[10], d_in[11] (lr_W, lr_b) dead too
    const float* lhW = (const float*)d_in[12];
    const float* lhb = (const float*)d_in[13];
    const float* att = (const float*)d_in[14];
    const float* l1W = (const float*)d_in[15];
    const float* l1b = (const float*)d_in[16];
    const float* l2W = (const float*)d_in[17];
    const float* l2b = (const float*)d_in[18];

    float* out = (float*)d_out;
    const int B = in_sizes[0] / (NN * FD * PP);   // 1024

    fused_k<<<B, 512, 0, stream>>>(x, ei, Wz, bz, Wh, bh, lzW, lzb, lhW, lhb,
                                   att, l1W, l1b, l2W, l2b, out);
}

// Round 9
// 129.920 us; speedup vs baseline: 1.0084x; 1.0084x over previous
//
#include <hip/hip_runtime.h>

#define NN   21   // nodes
#define NE   60   // edges (before self-loops)
#define FD   3    // input features
#define HD   32   // hidden
#define PP   64   // periods
#define OUTC 6    // output channels
#define LOG2E 1.44269504088896f

#if defined(__has_builtin)
#  if __has_builtin(__builtin_amdgcn_exp2f)
#    define EXP2(x) __builtin_amdgcn_exp2f(x)
#  else
#    define EXP2(x) exp2f(x)
#  endif
#else
#  define EXP2(x) exp2f(x)
#endif
#define RCP(x) __builtin_amdgcn_rcpf(x)

// ---------------------------------------------------------------------------
// Fully fused: ONE kernel, one block (512 thr = 8 waves) per batch element,
// no d_ws. Per-block parallel setup (~1us): deg scatter -> A[d][s] (rsqrt
// inline), W' = W@lW_top (log2e-prescaled), probs = softmax(att), Sc.
// Algebra (H=0): Hn = (1-Z)*tanh(..); no nonlinearity between l1 and l2:
//   out[c,p] = sum_o G[c,o]*l1W[o,p] + Sc[c]*l1b[p] + l2b[c],
//   G[c,o]   = sum_n l2W[n,c]*relu(sum_p probs[p]*(1-Z)*tanh).
// Gate eval (3 trans, 11 VALU): pr*(1-Z)*tanh = fmaf(pr,e2,-pr)*rcp((1+ea)(1+e2))
// NOTE (r7 lesson): do NOT hold x/l1W in registers across phases here —
// __launch_bounds__(512,8) caps VGPRs at 64 (compiler emits ~32) and the
// extra live state regressed 3us. LDS-write immediately; overlay l1W after
// stage 1 with a plain load (latency hides under stage-2 warmup anyway).
// ---------------------------------------------------------------------------
#define EVAL(Y0,Y1,Y2,PR) do {                                                  \
    float az0_ = fmaf((Y2), wz02, fmaf((Y1), wz01, fmaf((Y0), wz00, bz0)));     \
    float ah0_ = fmaf((Y2), wh02, fmaf((Y1), wh01, fmaf((Y0), wh00, bh0)));     \
    float ea0_ = EXP2(az0_), e20_ = EXP2(ah0_);                                 \
    float r0_  = RCP((1.f + ea0_) * (1.f + e20_));                              \
    acc0 = fmaf(fmaf((PR), e20_, -(PR)), r0_, acc0);                            \
    float az1_ = fmaf((Y2), wz12, fmaf((Y1), wz11, fmaf((Y0), wz10, bz1)));     \
    float ah1_ = fmaf((Y2), wh12, fmaf((Y1), wh11, fmaf((Y0), wh10, bh1)));     \
    float ea1_ = EXP2(az1_), e21_ = EXP2(ah1_);                                 \
    float r1_  = RCP((1.f + ea1_) * (1.f + e21_));                              \
    acc1 = fmaf(fmaf((PR), e21_, -(PR)), r1_, acc1);                            \
} while (0)

__global__ __launch_bounds__(512, 8) void fused_k(
    const float* __restrict__ x,   const int* __restrict__ edge,
    const float* __restrict__ Wz,  const float* __restrict__ bz,
    const float* __restrict__ Wh,  const float* __restrict__ bh,
    const float* __restrict__ lzW, const float* __restrict__ lzb,
    const float* __restrict__ lhW, const float* __restrict__ lhb,
    const float* __restrict__ att,
    const float* __restrict__ l1W, const float* __restrict__ l1b,
    const float* __restrict__ l2W, const float* __restrict__ l2b,
    float* __restrict__ out)
{
    // LDS: 16128 + 16128 + 2016 + 1408 + 2688 + 768 = 39136 B -> 4 blocks/CU
    __shared__ __align__(16) float Xs[NN * FD * PP]; // x[b]; post-stage1: l1W overlay
    __shared__ __align__(16) float Ys[NN * FD * PP]; // Y = A@X; post-stage2: M overlay
    __shared__ __align__(16) float AsP[NN * 24];     // padded adjacency
    __shared__ __align__(16) float Cs[352];          // W'z|W'h|b'z|b'h|probs|deg|Sc
    __shared__ float Hs[NN * HD];
    __shared__ float G[OUTC * HD];

    const int t = threadIdx.x;
    const int b = blockIdx.x;
    const float* xb = x + (size_t)b * (NN * FD * PP);

    // ---- Phase A: x -> Xs (float4, coalesced); zero A; deg = 1 (self-loop)
    {
        const float4* xb4 = (const float4*)xb;
        float4* Xs4 = (float4*)Xs;
        Xs4[t] = xb4[t];
        if (t < 496) Xs4[512 + t] = xb4[512 + t];     // 1008 float4 total
        for (int i = t; i < NN * 24; i += 512) AsP[i] = 0.f;
        if (t < NN) Cs[320 + t] = 1.f;
    }
    __syncthreads();

    // ---- Phase B: deg scatter | W' fusion | biases | softmax | Sc (disjoint)
    if (t < NE) {
        atomicAdd(&Cs[320 + edge[NE + t]], 1.f);
    } else if (t >= 64 && t < 160) {                  // W' = W @ lW_top, scaled
        int i = t - 64, f = i >> 5, o = i & 31;
        float az = 0.f, ah = 0.f;
        #pragma unroll
        for (int k = 0; k < HD; ++k) {
            az = fmaf(Wz[f * HD + k], lzW[k * HD + o], az);
            ah = fmaf(Wh[f * HD + k], lhW[k * HD + o], ah);
        }
        Cs[i] = az * LOG2E;                           // W'z
        Cs[96 + i] = ah * (2.f * LOG2E);              // W'h
    } else if (t >= 160 && t < 192) {                 // fused biases
        int o = t - 160;
        float az = lzb[o], ah = lhb[o];
        #pragma unroll
        for (int k = 0; k < HD; ++k) {
            az = fmaf(bz[k], lzW[k * HD + o], az);
            ah = fmaf(bh[k], lhW[k * HD + o], ah);
        }
        Cs[192 + o] = az * LOG2E;
        Cs[224 + o] = ah * (2.f * LOG2E);
    } else if (t >= 192 && t < 256) {                 // softmax(att), wave 3
        int l = t - 192;
        float a = att[l], m = a;
        #pragma unroll
        for (int msk = 32; msk >= 1; msk >>= 1) m = fmaxf(m, __shfl_xor(m, msk, 64));
        float e = __expf(a - m);
        float ssum = e;
        #pragma unroll
        for (int msk = 32; msk >= 1; msk >>= 1) ssum += __shfl_xor(ssum, msk, 64);
        Cs[256 + l] = e / ssum;
    } else if (t >= 256 && t < 256 + OUTC) {          // Sc[c] = sum_n l2W[n][c]
        int c = t - 256;
        float s = 0.f;
        for (int n = 0; n < NN; ++n) s += l2W[n * OUTC + c];
        Cs[344 + c] = s;
    }
    __syncthreads();

    // ---- Phase C: adjacency atomics, rsqrt inline (no extra barrier)
    if (t < NE) {
        int s = edge[t], d = edge[NE + t];
        atomicAdd(&AsP[d * 24 + s], rsqrtf(Cs[320 + s]) * rsqrtf(Cs[320 + d]));
    } else if (t >= 64 && t < 64 + NN) {
        int n = t - 64;
        atomicAdd(&AsP[n * 24 + n], RCP(Cs[320 + n]));  // dinv^2 = 1/deg
    }
    __syncthreads();

    // ---- Stage 1: Y = A @ X, skipping zero A entries (A ~82% zeros)
    {
        const float4* Xs4 = (const float4*)Xs;
        float4* Ys4 = (float4*)Ys;
        for (int i = t; i < NN * FD * PP / 4; i += 512) {
            const int p4 = i & 15;
            const int fn = i >> 4;            // n*3 + f
            const int n  = fn / 3;
            const int f  = fn - n * 3;
            const float4* An4 = (const float4*)(AsP + n * 24);
            float4 acc = {0.f, 0.f, 0.f, 0.f};
            #pragma unroll
            for (int mq = 0; mq < 6; ++mq) {
                const float4 a = An4[mq];
                if (a.x != 0.f) { const float4 xv = Xs4[((mq*4+0)*3+f)*16 + p4];
                    acc.x=fmaf(a.x,xv.x,acc.x); acc.y=fmaf(a.x,xv.y,acc.y);
                    acc.z=fmaf(a.x,xv.z,acc.z); acc.w=fmaf(a.x,xv.w,acc.w); }
                if (a.y != 0.f) { const float4 xv = Xs4[((mq*4+1)*3+f)*16 + p4];
                    acc.x=fmaf(a.y,xv.x,acc.x); acc.y=fmaf(a.y,xv.y,acc.y);
                    acc.z=fmaf(a.y,xv.z,acc.z); acc.w=fmaf(a.y,xv.w,acc.w); }
                if (a.z != 0.f) { const float4 xv = Xs4[((mq*4+2)*3+f)*16 + p4];
                    acc.x=fmaf(a.z,xv.x,acc.x); acc.y=fmaf(a.z,xv.y,acc.y);
                    acc.z=fmaf(a.z,xv.z,acc.z); acc.w=fmaf(a.z,xv.w,acc.w); }
                if (a.w != 0.f) { const float4 xv = Xs4[((mq*4+3)*3+f)*16 + p4];
                    acc.x=fmaf(a.w,xv.x,acc.x); acc.y=fmaf(a.w,xv.y,acc.y);
                    acc.z=fmaf(a.w,xv.z,acc.z); acc.w=fmaf(a.w,xv.w,acc.w); }
            }
            Ys4[fn * 16 + p4] = acc;
        }
    }
    __syncthreads();

    // ---- l1W -> dead Xs region (global load + LDS write; Xs reads done)
    ((float4*)Xs)[t] = ((const float4*)l1W)[t];       // 512 x 16B = 2048 floats

    // ---- Stage 2: Hpool[n][o] = sum_p probs[p]*(1-Z)*tanh ; relu fused
    // lane: ps = t&7 (8 p's), o-pair = (t>>3)&15, n-offset = t>>7; p-sum via shfl
    {
        const int ps = t & 7;
        const int og = (t >> 3) & 15;
        const int c4 = t >> 7;                        // 0..3, wave-uniform
        const int o0 = og * 2, o1 = o0 + 1;
        const float wz00 = Cs[o0],     wz01 = Cs[32+o0],  wz02 = Cs[64+o0];
        const float wz10 = Cs[o1],     wz11 = Cs[32+o1],  wz12 = Cs[64+o1];
        const float wh00 = Cs[96+o0],  wh01 = Cs[128+o0], wh02 = Cs[160+o0];
        const float wh10 = Cs[96+o1],  wh11 = Cs[128+o1], wh12 = Cs[160+o1];
        const float bz0  = Cs[192+o0], bz1  = Cs[192+o1];
        const float bh0  = Cs[224+o0], bh1  = Cs[224+o1];
        const float4 pr0 = *(const float4*)&Cs[256 + ps*8];
        const float4 pr1 = *(const float4*)&Cs[256 + ps*8 + 4];
        #pragma unroll
        for (int s = 0; s < 6; ++s) {
            const int n = c4 + 4 * s;
            if (n < NN) {                             // wave-uniform guard
                const float4* Yn4 = (const float4*)(Ys + n * FD * PP) + ps * 2;
                float acc0 = 0.f, acc1 = 0.f;
                float4 y0 = Yn4[0], y1 = Yn4[16], y2 = Yn4[32];
                EVAL(y0.x,y1.x,y2.x, pr0.x); EVAL(y0.y,y1.y,y2.y, pr0.y);
                EVAL(y0.z,y1.z,y2.z, pr0.z); EVAL(y0.w,y1.w,y2.w, pr0.w);
                y0 = Yn4[1]; y1 = Yn4[17]; y2 = Yn4[33];
                EVAL(y0.x,y1.x,y2.x, pr1.x); EVAL(y0.y,y1.y,y2.y, pr1.y);
                EVAL(y0.z,y1.z,y2.z, pr1.z); EVAL(y0.w,y1.w,y2.w, pr1.w);
                acc0 += __shfl_xor(acc0, 1); acc0 += __shfl_xor(acc0, 2); acc0 += __shfl_xor(acc0, 4);
                acc1 += __shfl_xor(acc1, 1); acc1 += __shfl_xor(acc1, 2); acc1 += __shfl_xor(acc1, 4);
                if (ps == 0) {
                    Hs[n * HD + o0] = fmaxf(acc0, 0.f);
                    Hs[n * HD + o1] = fmaxf(acc1, 0.f);
                }
            }
        }
    }
    __syncthreads();

    // ---- Stage 3': G[c,o] (t<192)  ||  M[c,p] -> dead Ys[0..383] (t>=192)
    if (t < OUTC * HD) {
        const int c = t >> 5, o = t & 31;
        float g = 0.f;
        #pragma unroll
        for (int n = 0; n < NN; ++n)
            g = fmaf(l2W[n * OUTC + c], Hs[n * HD + o], g);
        G[t] = g;
    } else {
        for (int i = t - 192; i < OUTC * PP; i += 320) {
            const int c = i >> 6, p = i & 63;
            Ys[i] = fmaf(Cs[344 + c], l1b[p], l2b[c]);
        }
    }
    __syncthreads();

    // ---- Stage 4': out[b,c,p] = sum_o G[c,o]*l1W[o,p] + M[c,p]
    if (t < OUTC * PP) {
        const int c = t >> 6, p = t & 63;
        const float* Gc = G + c * HD;
        const float* l1Ws = Xs;                       // overlaid [32][64]
        float a0 = 0.f, a1 = 0.f, a2 = 0.f, a3 = 0.f;
        #pragma unroll
        for (int o = 0; o < HD; o += 4) {
            a0 = fmaf(Gc[o+0], l1Ws[(o+0) * PP + p], a0);
            a1 = fmaf(Gc[o+1], l1Ws[(o+1) * PP + p], a1);
            a2 = fmaf(Gc[o+2], l1Ws[(o+2) * PP + p], a2);
            a3 = fmaf(Gc[o+3], l1Ws[(o+3) * PP + p], a3);
        }
        out[(size_t)b * (OUTC * PP) + t] = Ys[t] + (a0 + a1) + (a2 + a3);
    }
}

extern "C" void kernel_launch(void* const* d_in, const int* in_sizes, int n_in,
                              void* d_out, int out_size, void* d_ws, size_t ws_size,
                              hipStream_t stream) {
    const float* x   = (const float*)d_in[0];
    const int*   ei  = (const int*)  d_in[1];
    const float* Wz  = (const float*)d_in[2];
    const float* bz  = (const float*)d_in[3];
    // d_in[4], d_in[5] (W_r, b_r) dead: H=0 -> reset gate never used
    const float* Wh  = (const float*)d_in[6];
    const float* bh  = (const float*)d_in[7];
    const float* lzW = (const float*)d_in[8];
    const float* lzb = (const float*)d_in[9];
    // d_in[10], d_in[11] (lr_W, lr_b) dead too
    const float* lhW = (const float*)d_in[12];
    const float* lhb = (const float*)d_in[13];
    const float* att = (const float*)d_in[14];
    const float* l1W = (const float*)d_in[15];
    const float* l1b = (const float*)d_in[16];
    const float* l2W = (const float*)d_in[17];
    const float* l2b = (const float*)d_in[18];

    float* out = (float*)d_out;
    const int B = in_sizes[0] / (NN * FD * PP);   // 1024

    fused_k<<<B, 512, 0, stream>>>(x, ei, Wz, bz, Wh, bh, lzW, lzb, lhW, lhb,
                                   att, l1W, l1b, l2W, l2b, out);
}